// Round 1
// baseline (2738.496 us; speedup 1.0000x reference)
//
#include <hip/hip_runtime.h>
#include <math.h>

#define B_  8
#define C_  64
#define H_  128
#define W_  128
#define KK_ 9
#define CO_ 64
#define HW_ (H_*W_)

// ---------------- Kernel A: 3x3 offset conv (27 output maps) ----------------
// grid: B * 27 * (HW/256); block 256. w_off row staged in LDS.
__global__ __launch_bounds__(256) void off_conv_kernel(
    const float* __restrict__ x, const float* __restrict__ w_off,
    const float* __restrict__ b_off, float* __restrict__ pdy,
    float* __restrict__ pdx, float* __restrict__ pm)
{
    __shared__ float wsm[C_ * 9];
    int bid  = blockIdx.x;
    int tile = bid & 63;            // HW/256 = 64 tiles
    int j    = (bid >> 6) % 27;
    int b    = bid / (64 * 27);

    for (int i = threadIdx.x; i < C_ * 9; i += 256)
        wsm[i] = w_off[j * C_ * 9 + i];
    __syncthreads();

    int p  = tile * 256 + threadIdx.x;
    int y  = p >> 7;                // W = 128
    int xx = p & 127;

    float acc = b_off[j];
    const float* xb = x + (size_t)b * C_ * HW_;
    for (int c = 0; c < C_; ++c) {
        const float* xc = xb + c * HW_;
        const float* wr = &wsm[c * 9];
        #pragma unroll
        for (int ky = 0; ky < 3; ++ky) {
            int yy = y + ky - 1;
            if (yy < 0 || yy >= H_) continue;
            const float* row = xc + yy * W_;
            #pragma unroll
            for (int kx = 0; kx < 3; ++kx) {
                int xi = xx + kx - 1;
                if (xi < 0 || xi >= W_) continue;
                acc += wr[ky * 3 + kx] * row[xi];
            }
        }
    }

    if (j < 18) {
        int k = j >> 1;
        float* dst = (j & 1) ? pdx : pdy;   // om[2k] = dy, om[2k+1] = dx
        dst[(b * KK_ + k) * HW_ + p] = acc;
    } else {
        int k = j - 18;
        pm[(b * KK_ + k) * HW_ + p] = 1.0f / (1.0f + expf(-acc));
    }
}

// ---------------- Kernel T: NCHW -> NHWC transpose of x ----------------
// grid: B * (HW/64); block 256. LDS tile 64c x 64pix, pad stride 65.
__global__ __launch_bounds__(256) void transpose_kernel(
    const float* __restrict__ x, float* __restrict__ xt)
{
    __shared__ float t[64 * 65];
    int bid = blockIdx.x;
    int b = bid >> 8;               // HW/64 = 256 tiles per batch
    int pixbase = (bid & 255) * 64;
    #pragma unroll
    for (int i = 0; i < 16; ++i) {
        int idx = i * 256 + threadIdx.x;
        int c = idx >> 6;
        int pix = idx & 63;
        t[c * 65 + pix] = x[((size_t)b * C_ + c) * HW_ + pixbase + pix];
    }
    __syncthreads();
    #pragma unroll
    for (int i = 0; i < 16; ++i) {
        int idx = i * 256 + threadIdx.x;
        int c = idx & 63;
        int pix = idx >> 6;
        xt[((size_t)b * HW_ + pixbase + pix) * C_ + c] = t[c * 65 + pix];
    }
}

// ---------------- Kernel C: bilinear sample + mask + (C*K) contraction ------
// 4 pixels / block (one wave each). Stage 1: lane = channel c, 9 taps -> LDS.
// Stage 2: lane = out channel o, 576-MAC dot with w_dcn row.
template<bool NHWC>
__global__ __launch_bounds__(256) void dcn_kernel(
    const float* __restrict__ xs, const float* __restrict__ pdy,
    const float* __restrict__ pdx, const float* __restrict__ pm,
    const float* __restrict__ w_dcn, float* __restrict__ out)
{
    __shared__ float s[4][C_ * KK_];
    int lane  = threadIdx.x & 63;
    int group = threadIdx.x >> 6;
    int pix = blockIdx.x * 4 + group;
    int b = pix >> 14;              // HW = 16384
    int p = pix & 16383;
    int y  = p >> 7;
    int xx = p & 127;
    int c = lane;

    #pragma unroll
    for (int k = 0; k < KK_; ++k) {
        int oidx = (b * KK_ + k) * HW_ + p;
        float dy = pdy[oidx];
        float dx = pdx[oidx];
        float m  = pm[oidx];
        float py = dy + (float)(y - 1 + k / 3);
        float px = dx + (float)(xx - 1 + k % 3);
        float fy = floorf(py), fx = floorf(px);
        int y0 = (int)fy, x0 = (int)fx;
        float ay = py - fy, ax = px - fx;
        float w00 = (1.f - ay) * (1.f - ax);
        float w01 = (1.f - ay) * ax;
        float w10 = ay * (1.f - ax);
        float w11 = ay * ax;
        bool y0v = (y0 >= 0) && (y0 < H_);
        bool y1v = (y0 + 1 >= 0) && (y0 + 1 < H_);
        bool x0v = (x0 >= 0) && (x0 < W_);
        bool x1v = (x0 + 1 >= 0) && (x0 + 1 < W_);

        float v = 0.f;
        if (NHWC) {
            const float* xb = xs + (size_t)b * HW_ * C_;
            if (y0v) {
                const float* r = xb + (size_t)y0 * W_ * C_;
                if (x0v) v += w00 * r[x0 * C_ + c];
                if (x1v) v += w01 * r[(x0 + 1) * C_ + c];
            }
            if (y1v) {
                const float* r = xb + (size_t)(y0 + 1) * W_ * C_;
                if (x0v) v += w10 * r[x0 * C_ + c];
                if (x1v) v += w11 * r[(x0 + 1) * C_ + c];
            }
        } else {
            const float* xc = xs + ((size_t)b * C_ + c) * HW_;
            if (y0v) {
                const float* r = xc + y0 * W_;
                if (x0v) v += w00 * r[x0];
                if (x1v) v += w01 * r[x0 + 1];
            }
            if (y1v) {
                const float* r = xc + (y0 + 1) * W_;
                if (x0v) v += w10 * r[x0];
                if (x1v) v += w11 * r[x0 + 1];
            }
        }
        s[group][c * KK_ + k] = v * m;   // stride 9 across lanes: 9 coprime 32 -> conflict-free
    }
    __syncthreads();

    int o = lane;
    const float* wr = w_dcn + o * C_ * KK_;
    const float* sg = s[group];
    float acc = 0.f;
    #pragma unroll 8
    for (int ck = 0; ck < C_ * KK_; ++ck)
        acc += sg[ck] * wr[ck];        // LDS read is wave-broadcast (free)
    out[((size_t)b * CO_ + o) * HW_ + p] = acc;
}

extern "C" void kernel_launch(void* const* d_in, const int* in_sizes, int n_in,
                              void* d_out, int out_size, void* d_ws, size_t ws_size,
                              hipStream_t stream)
{
    const float* x     = (const float*)d_in[0];
    const float* w_off = (const float*)d_in[1];
    const float* b_off = (const float*)d_in[2];
    const float* w_dcn = (const float*)d_in[3];
    float* out = (float*)d_out;

    size_t offs_elems = (size_t)B_ * KK_ * HW_;      // 1179648
    float* pdy = (float*)d_ws;
    float* pdx = pdy + offs_elems;
    float* pm  = pdx + offs_elems;
    float* xt  = pm + offs_elems;
    size_t need_full = (3 * offs_elems + (size_t)B_ * C_ * HW_) * sizeof(float);
    bool nhwc = (ws_size >= need_full);

    off_conv_kernel<<<B_ * 27 * (HW_ / 256), 256, 0, stream>>>(
        x, w_off, b_off, pdy, pdx, pm);

    if (nhwc) {
        transpose_kernel<<<B_ * (HW_ / 64), 256, 0, stream>>>(x, xt);
        dcn_kernel<true><<<B_ * HW_ / 4, 256, 0, stream>>>(
            xt, pdy, pdx, pm, w_dcn, out);
    } else {
        dcn_kernel<false><<<B_ * HW_ / 4, 256, 0, stream>>>(
            x, pdy, pdx, pm, w_dcn, out);
    }
}

// Round 2
// 468.752 us; speedup vs baseline: 5.8421x; 5.8421x over previous
//
#include <hip/hip_runtime.h>
#include <math.h>

#define B_  8
#define C_  64
#define H_  128
#define W_  128
#define KK_ 9
#define CO_ 64
#define HW_ (H_*W_)
#define CK_ 576          // C*KK
#define CHC 16           // channels per chunk
#define CHJ 144          // CHC*9  (K-chunk)
#define SROW 68          // padded LDS row stride (16B-aligned float4 rows)

// ---------------- Kernel A v2: 3x3 offset conv, all 27 maps per block -------
// Block = 2 rows x 128 cols. x tile chunk in LDS; w_off via uniform scalar
// loads (SMEM path, zero LDS/VALU cost). 27 accumulators per thread.
__global__ __launch_bounds__(256) void off_conv2(
    const float* __restrict__ x, const float* __restrict__ w_off,
    const float* __restrict__ b_off, float* __restrict__ pdy,
    float* __restrict__ pdx, float* __restrict__ pm)
{
    __shared__ float xs[CHC][4][132];   // [c][row y0-1..y0+2][xcoord+1]
    int b  = blockIdx.x >> 6;
    int y0 = (blockIdx.x & 63) * 2;
    int t   = threadIdx.x;
    int row = t >> 7;        // 0..1
    int col = t & 127;       // x coordinate

    float acc[27];
    #pragma unroll
    for (int j = 0; j < 27; ++j) acc[j] = 0.f;

    for (int cc = 0; cc < 4; ++cc) {
        // stage x chunk: 16 ch x 4 rows x 130 cols (zero-padded borders)
        for (int i = t; i < CHC * 4 * 130; i += 256) {
            int c_l = i / 520;
            int r   = i % 520;
            int ry  = r / 130;
            int cx  = r % 130;
            int yy  = y0 - 1 + ry;
            int xx  = cx - 1;
            float v = 0.f;
            if (yy >= 0 && yy < H_ && xx >= 0 && xx < W_)
                v = x[((size_t)(b * C_ + cc * CHC + c_l) * H_ + yy) * W_ + xx];
            xs[c_l][ry][cx] = v;
        }
        __syncthreads();

        for (int c_l = 0; c_l < CHC; ++c_l) {
            float n[9];
            #pragma unroll
            for (int ky = 0; ky < 3; ++ky)
                #pragma unroll
                for (int kx = 0; kx < 3; ++kx)
                    n[ky * 3 + kx] = xs[c_l][row + ky][col + kx];
            // uniform pointer -> scalar (SMEM) loads for weights
            const float* __restrict__ wp = w_off + (cc * CHC + c_l) * 9;
            #pragma unroll
            for (int j = 0; j < 27; ++j) {
                float a = acc[j];
                #pragma unroll
                for (int k = 0; k < 9; ++k)
                    a += wp[j * CK_ + k] * n[k];
                acc[j] = a;
            }
        }
        __syncthreads();
    }

    int p = (y0 + row) * W_ + col;
    #pragma unroll
    for (int j = 0; j < 27; ++j) {
        float v = acc[j] + b_off[j];
        if (j < 18) {
            int k = j >> 1;
            float* dst = (j & 1) ? pdx : pdy;   // om[2k]=dy, om[2k+1]=dx
            dst[(b * KK_ + k) * HW_ + p] = v;
        } else {
            pm[(b * KK_ + (j - 18)) * HW_ + p] = 1.f / (1.f + expf(-v));
        }
    }
}

// ---------------- Kernel T: NCHW -> NHWC transpose of x ----------------
__global__ __launch_bounds__(256) void transpose_kernel(
    const float* __restrict__ x, float* __restrict__ xt)
{
    __shared__ float tbuf[64 * 65];
    int bid = blockIdx.x;
    int b = bid >> 8;
    int pixbase = (bid & 255) * 64;
    #pragma unroll
    for (int i = 0; i < 16; ++i) {
        int idx = i * 256 + threadIdx.x;
        int c = idx >> 6;
        int pix = idx & 63;
        tbuf[c * 65 + pix] = x[((size_t)b * C_ + c) * HW_ + pixbase + pix];
    }
    __syncthreads();
    #pragma unroll
    for (int i = 0; i < 16; ++i) {
        int idx = i * 256 + threadIdx.x;
        int c = idx & 63;
        int pix = idx >> 6;
        xt[((size_t)b * HW_ + pixbase + pix) * C_ + c] = tbuf[c * 65 + pix];
    }
}

// ---------------- Kernel C v2: fused bilinear sample + tiled GEMM -----------
// Block: 64 pixels x 64 out-channels. Chunked K (144) through LDS; 4x4
// register tile per thread; ds_read_b128 on both operands.
template<bool NHWC>
__global__ __launch_bounds__(256) void dcn2(
    const float* __restrict__ xs, const float* __restrict__ pdy,
    const float* __restrict__ pdx, const float* __restrict__ pm,
    const float* __restrict__ w_dcn, float* __restrict__ out)
{
    __shared__ float sS[CHJ * SROW];   // sampled [j_local][pixel]
    __shared__ float sW[CHJ * SROW];   // weights  [j_local][o]
    int tile = blockIdx.x;
    int b  = tile >> 8;
    int p0 = (tile & 255) * 64;
    int y  = p0 >> 7;                  // row (64 pixels stay in one row)
    int x0 = p0 & 127;
    int t  = threadIdx.x;

    // GEMM mapping: 4 o x 4 p per thread
    int o4 = (t & 15) * 4;
    int pq = (t >> 4) * 4;
    // sampling mapping: pixel sp, k-set sg
    int sp = t & 63;
    int sg = t >> 6;
    int px_i = x0 + sp;

    float acc[4][4];
    #pragma unroll
    for (int i = 0; i < 4; ++i)
        #pragma unroll
        for (int j = 0; j < 4; ++j) acc[i][j] = 0.f;

    for (int cc = 0; cc < 4; ++cc) {
        // stage transposed weight chunk: sW[j][o] = w_dcn[o*576 + cc*144 + j]
        for (int i = t; i < CHJ * 64; i += 256) {
            int o = i / CHJ;
            int j = i % CHJ;
            sW[j * SROW + o] = w_dcn[o * CK_ + cc * CHJ + j];
        }
        // sampling: this wave's k list = {sg, sg+4, sg+8(<9)}
        #pragma unroll
        for (int kk = 0; kk < 3; ++kk) {
            int k = sg + kk * 4;
            if (k < 9) {
                int oidx = (b * KK_ + k) * HW_ + p0 + sp;
                float dy = pdy[oidx];
                float dx = pdx[oidx];
                float m  = pm[oidx];
                float py = dy + (float)(y - 1 + k / 3);
                float px = dx + (float)(px_i - 1 + k % 3);
                float fy = floorf(py), fx = floorf(px);
                int iy = (int)fy, ix = (int)fx;
                float ay = py - fy, ax = px - fx;
                float wy0 = 1.f - ay, wy1 = ay;
                float wx0 = 1.f - ax, wx1 = ax;
                if (iy < 0 || iy >= H_)         wy0 = 0.f;
                if (iy + 1 < 0 || iy + 1 >= H_) wy1 = 0.f;
                if (ix < 0 || ix >= W_)         wx0 = 0.f;
                if (ix + 1 < 0 || ix + 1 >= W_) wx1 = 0.f;
                int iy0 = min(max(iy, 0), H_ - 1);
                int iy1 = min(max(iy + 1, 0), H_ - 1);
                int ix0 = min(max(ix, 0), W_ - 1);
                int ix1 = min(max(ix + 1, 0), W_ - 1);
                float w00 = wy0 * wx0 * m, w01 = wy0 * wx1 * m;
                float w10 = wy1 * wx0 * m, w11 = wy1 * wx1 * m;

                if (NHWC) {
                    const float* base = xs + (size_t)b * HW_ * C_ + cc * CHC;
                    const float* r00 = base + (size_t)(iy0 * W_ + ix0) * C_;
                    const float* r01 = base + (size_t)(iy0 * W_ + ix1) * C_;
                    const float* r10 = base + (size_t)(iy1 * W_ + ix0) * C_;
                    const float* r11 = base + (size_t)(iy1 * W_ + ix1) * C_;
                    #pragma unroll
                    for (int c4 = 0; c4 < 4; ++c4) {
                        const float4 v00 = *(const float4*)(r00 + c4 * 4);
                        const float4 v01 = *(const float4*)(r01 + c4 * 4);
                        const float4 v10 = *(const float4*)(r10 + c4 * 4);
                        const float4 v11 = *(const float4*)(r11 + c4 * 4);
                        float e0 = w00*v00.x + w01*v01.x + w10*v10.x + w11*v11.x;
                        float e1 = w00*v00.y + w01*v01.y + w10*v10.y + w11*v11.y;
                        float e2 = w00*v00.z + w01*v01.z + w10*v10.z + w11*v11.z;
                        float e3 = w00*v00.w + w01*v01.w + w10*v10.w + w11*v11.w;
                        sS[((c4*4 + 0)*9 + k) * SROW + sp] = e0;
                        sS[((c4*4 + 1)*9 + k) * SROW + sp] = e1;
                        sS[((c4*4 + 2)*9 + k) * SROW + sp] = e2;
                        sS[((c4*4 + 3)*9 + k) * SROW + sp] = e3;
                    }
                } else {
                    #pragma unroll
                    for (int c4 = 0; c4 < 4; ++c4) {
                        #pragma unroll
                        for (int i2 = 0; i2 < 4; ++i2) {
                            int c = cc * CHC + c4 * 4 + i2;
                            const float* xc = xs + (size_t)(b * C_ + c) * HW_;
                            float v = w00 * xc[iy0 * W_ + ix0]
                                    + w01 * xc[iy0 * W_ + ix1]
                                    + w10 * xc[iy1 * W_ + ix0]
                                    + w11 * xc[iy1 * W_ + ix1];
                            sS[((c4*4 + i2)*9 + k) * SROW + sp] = v;
                        }
                    }
                }
            }
        }
        __syncthreads();

        // GEMM over this K-chunk
        #pragma unroll 4
        for (int j = 0; j < CHJ; ++j) {
            const float4 w4 = *(const float4*)&sW[j * SROW + o4];
            const float4 s4 = *(const float4*)&sS[j * SROW + pq];
            acc[0][0] += w4.x * s4.x; acc[0][1] += w4.x * s4.y;
            acc[0][2] += w4.x * s4.z; acc[0][3] += w4.x * s4.w;
            acc[1][0] += w4.y * s4.x; acc[1][1] += w4.y * s4.y;
            acc[1][2] += w4.y * s4.z; acc[1][3] += w4.y * s4.w;
            acc[2][0] += w4.z * s4.x; acc[2][1] += w4.z * s4.y;
            acc[2][2] += w4.z * s4.z; acc[2][3] += w4.z * s4.w;
            acc[3][0] += w4.w * s4.x; acc[3][1] += w4.w * s4.y;
            acc[3][2] += w4.w * s4.z; acc[3][3] += w4.w * s4.w;
        }
        __syncthreads();
    }

    #pragma unroll
    for (int oi = 0; oi < 4; ++oi) {
        float4 v;
        v.x = acc[oi][0]; v.y = acc[oi][1]; v.z = acc[oi][2]; v.w = acc[oi][3];
        *(float4*)&out[((size_t)(b * CO_ + o4 + oi)) * HW_ + p0 + pq] = v;
    }
}

extern "C" void kernel_launch(void* const* d_in, const int* in_sizes, int n_in,
                              void* d_out, int out_size, void* d_ws, size_t ws_size,
                              hipStream_t stream)
{
    const float* x     = (const float*)d_in[0];
    const float* w_off = (const float*)d_in[1];
    const float* b_off = (const float*)d_in[2];
    const float* w_dcn = (const float*)d_in[3];
    float* out = (float*)d_out;

    size_t offs_elems = (size_t)B_ * KK_ * HW_;
    float* pdy = (float*)d_ws;
    float* pdx = pdy + offs_elems;
    float* pm  = pdx + offs_elems;
    float* xt  = pm + offs_elems;
    size_t need_full = (3 * offs_elems + (size_t)B_ * C_ * HW_) * sizeof(float);
    bool nhwc = (ws_size >= need_full);

    off_conv2<<<B_ * (H_ / 2), 256, 0, stream>>>(x, w_off, b_off, pdy, pdx, pm);

    if (nhwc) {
        transpose_kernel<<<B_ * (HW_ / 64), 256, 0, stream>>>(x, xt);
        dcn2<true><<<B_ * (HW_ / 64), 256, 0, stream>>>(
            xt, pdy, pdx, pm, w_dcn, out);
    } else {
        dcn2<false><<<B_ * (HW_ / 64), 256, 0, stream>>>(
            x, pdy, pdx, pm, w_dcn, out);
    }
}

// Round 3
// 331.523 us; speedup vs baseline: 8.2604x; 1.4139x over previous
//
#include <hip/hip_runtime.h>
#include <math.h>

#define B_  8
#define C_  64
#define H_  128
#define W_  128
#define KK_ 9
#define CO_ 64
#define HW_ (H_*W_)
#define CK_ 576

typedef __attribute__((ext_vector_type(8)))  short bf16x8;
typedef __attribute__((ext_vector_type(16))) float f32x16;

__device__ inline float blo(unsigned u){ union{unsigned v;float f;}c; c.v = u<<16;          return c.f; }
__device__ inline float bhi(unsigned u){ union{unsigned v;float f;}c; c.v = u & 0xffff0000u; return c.f; }
__device__ inline unsigned pack_bf16x2(float a, float b){
    union{float f;unsigned u;} ua, ub; ua.f=a; ub.f=b;
    unsigned ra = ua.u + 0x7fffu + ((ua.u>>16)&1u);
    unsigned rb = ub.u + 0x7fffu + ((ub.u>>16)&1u);
    return (ra>>16) | (rb & 0xffff0000u);
}

// ---------------- prep_w: w_dcn (o,c,tap) fp32 -> w_bf[o][tap*64+c] bf16 ----
__global__ __launch_bounds__(256) void prep_w(const float* __restrict__ w_dcn,
                                              unsigned short* __restrict__ w_bf)
{
    int i = blockIdx.x * 256 + threadIdx.x;       // 64*576 = 36864
    int o = i / CK_;
    int r = i % CK_;
    int tap = r >> 6;
    int c = r & 63;
    union{float f;unsigned u;} uu; uu.f = w_dcn[o * CK_ + c * 9 + tap];
    unsigned rr = uu.u + 0x7fffu + ((uu.u>>16)&1u);
    w_bf[i] = (unsigned short)(rr >> 16);
}

// ---------------- transpose_bf: x NCHW fp32 -> xt NHWC bf16 (as dwords) -----
__global__ __launch_bounds__(256) void transpose_bf(const float* __restrict__ x,
                                                    unsigned* __restrict__ xt)
{
    __shared__ float tb[64 * 65];
    int b = blockIdx.x >> 8;
    int pixbase = (blockIdx.x & 255) * 64;
    #pragma unroll
    for (int i = 0; i < 16; ++i) {
        int idx = i * 256 + threadIdx.x;
        int c = idx >> 6, pix = idx & 63;
        tb[c * 65 + pix] = x[((size_t)(b * C_ + c)) * HW_ + pixbase + pix];
    }
    __syncthreads();
    #pragma unroll
    for (int i = 0; i < 8; ++i) {
        int idx = i * 256 + threadIdx.x;          // 0..2047
        int pix = idx >> 5, cp = idx & 31;
        float f0 = tb[(2*cp)   * 65 + pix];
        float f1 = tb[(2*cp+1) * 65 + pix];
        xt[((size_t)b * HW_ + pixbase + pix) * 32 + cp] = pack_bf16x2(f0, f1);
    }
}

// ---------------- off_conv3: 3x3 offset conv, j-split (9 maps/block) --------
__global__ __launch_bounds__(256) void off_conv3(
    const float* __restrict__ x, const float* __restrict__ w_off,
    const float* __restrict__ b_off, float* __restrict__ pdy,
    float* __restrict__ pdx, float* __restrict__ pm)
{
    __shared__ float xs[16][4][132];
    int bid = blockIdx.x;
    int g  = bid % 3;
    int y0 = ((bid / 3) & 63) * 2;
    int b  = bid / (3 * 64);
    int j0 = g * 9;
    int t = threadIdx.x;
    int row = t >> 7, col = t & 127;

    float acc[9];
    #pragma unroll
    for (int j = 0; j < 9; ++j) acc[j] = 0.f;

    for (int cc = 0; cc < 4; ++cc) {
        for (int i = t; i < 16 * 4 * 130; i += 256) {
            int c_l = i / 520;
            int r = i % 520;
            int ry = r / 130, cx = r % 130;
            int yy = y0 - 1 + ry, xx = cx - 1;
            float v = 0.f;
            if (yy >= 0 && yy < H_ && xx >= 0 && xx < W_)
                v = x[((size_t)(b * C_ + cc * 16 + c_l) * H_ + yy) * W_ + xx];
            xs[c_l][ry][cx] = v;
        }
        __syncthreads();
        for (int c_l = 0; c_l < 16; ++c_l) {
            float n[9];
            #pragma unroll
            for (int ky = 0; ky < 3; ++ky)
                #pragma unroll
                for (int kx = 0; kx < 3; ++kx)
                    n[ky * 3 + kx] = xs[c_l][row + ky][col + kx];
            const float* __restrict__ wp = w_off + (size_t)j0 * CK_ + (cc * 16 + c_l) * 9;
            #pragma unroll
            for (int j = 0; j < 9; ++j) {
                float a = acc[j];
                #pragma unroll
                for (int k = 0; k < 9; ++k)
                    a += wp[j * CK_ + k] * n[k];
                acc[j] = a;
            }
        }
        __syncthreads();
    }
    int p = (y0 + row) * W_ + col;
    #pragma unroll
    for (int j = 0; j < 9; ++j) {
        int jg = j0 + j;
        float v = acc[j] + b_off[jg];
        if (jg < 18) {
            int k = jg >> 1;
            float* dst = (jg & 1) ? pdx : pdy;    // om[2k]=dy, om[2k+1]=dx
            dst[(b * KK_ + k) * HW_ + p] = v;
        } else {
            pm[(b * KK_ + (jg - 18)) * HW_ + p] = 1.f / (1.f + expf(-v));
        }
    }
}

// ---------------- dcn3: bilinear sample (bf16) + MFMA 32x32x16 GEMM ---------
// Block: 64 pixels x 64 out-ch; K=576 tap-major in 2 chunks (taps 0-4, 5-8).
#define SSTRB 656                 // sS row bytes: (320+8 pad)*2, 16B-aligned
__global__ __launch_bounds__(256) void dcn3(
    const unsigned* __restrict__ xt,             // bf16x2 NHWC
    const float* __restrict__ pdy, const float* __restrict__ pdx,
    const float* __restrict__ pm,
    const unsigned short* __restrict__ w_bf,     // [o][tap*64+c] bf16
    float* __restrict__ out)
{
    __shared__ unsigned char sS[64 * SSTRB];     // sampled [p][k_local] bf16
    __shared__ float4 scr_w[576];                // corner weights * mask
    __shared__ int    scr_o[576];                // packed corner offsets

    int tile = blockIdx.x;
    int b  = tile >> 8;
    int p0 = (tile & 255) * 64;
    int y  = p0 >> 7;
    int x0 = p0 & 127;
    int t  = threadIdx.x;

    // Phase 0: offsets -> bilinear weights + packed corner byte-offsets
    for (int i = t; i < 576; i += 256) {
        int k = i >> 6, sp = i & 63;
        int oidx = (b * KK_ + k) * HW_ + p0 + sp;
        float dy = pdy[oidx], dx = pdx[oidx], m = pm[oidx];
        float py = dy + (float)(y - 1 + k / 3);
        float px = dx + (float)(x0 + sp - 1 + k % 3);
        float fy = floorf(py), fx = floorf(px);
        int iy = (int)fy, ix = (int)fx;
        float ay = py - fy, ax = px - fx;
        float wy0 = (iy >= 0  && iy < H_)     ? (1.f - ay) : 0.f;
        float wy1 = (iy >= -1 && iy < H_ - 1) ? ay         : 0.f;
        float wx0 = (ix >= 0  && ix < W_)     ? (1.f - ax) : 0.f;
        float wx1 = (ix >= -1 && ix < W_ - 1) ? ax         : 0.f;
        int iy0 = min(max(iy, 0), H_ - 1);
        int iy1 = min(max(iy + 1, 0), H_ - 1);
        int ix0 = min(max(ix, 0), W_ - 1);
        int ix1 = min(max(ix + 1, 0), W_ - 1);
        scr_w[i] = make_float4(wy0*wx0*m, wy0*wx1*m, wy1*wx0*m, wy1*wx1*m);
        int off00 = (iy0 * W_ + ix0) * 128;      // bytes (64ch * 2B bf16)
        scr_o[i] = off00 | ((ix1 != ix0) << 22) | ((iy1 != iy0) << 23);
    }
    __syncthreads();

    int lane = t & 63;
    int w    = t >> 6;
    int ow = (w >> 1) * 32;        // wave's o-quadrant
    int pw = (w & 1) * 32;         // wave's p-quadrant
    int cp = lane & 31;            // channel pair (2 ch)
    int ph = lane >> 5;            // which of 2 pixels (sampling) / k-half (gemm)

    f32x16 acc = {};
    const unsigned char* xb = (const unsigned char*)xt + (size_t)b * HW_ * 128;

    int tap0 = 0, koff = 0;
    #pragma unroll
    for (int chunk = 0; chunk < 2; ++chunk) {
        int ntap = chunk ? 4 : 5;
        // ---- sampling: 2 pixels per wave-iter, 4 corner loads, fp32 acc ----
        int niter = ntap * 8;                    // ntap*32 pairs / 4 waves
        for (int it = 0; it < niter; ++it) {
            int pi = w * niter + it;
            int ktl = pi >> 5;
            int sp  = (pi & 31) * 2 + ph;
            int idx = (tap0 + ktl) * 64 + sp;
            float4 w4 = scr_w[idx];
            int pk = scr_o[idx];
            int off00 = pk & 0x3FFFFF;
            int dxb = (pk >> 15) & 128;          // bit22 -> 128 B
            int dyb = (pk >> 9)  & 16384;        // bit23 -> 16384 B
            const unsigned char* a00 = xb + off00 + cp * 4;
            unsigned u00 = *(const unsigned*)(a00);
            unsigned u01 = *(const unsigned*)(a00 + dxb);
            unsigned u10 = *(const unsigned*)(a00 + dyb);
            unsigned u11 = *(const unsigned*)(a00 + dyb + dxb);
            float lo = w4.x*blo(u00) + w4.y*blo(u01) + w4.z*blo(u10) + w4.w*blo(u11);
            float hi = w4.x*bhi(u00) + w4.y*bhi(u01) + w4.z*bhi(u10) + w4.w*bhi(u11);
            *(unsigned*)&sS[sp * SSTRB + ktl * 128 + cp * 4] = pack_bf16x2(lo, hi);
        }
        __syncthreads();

        // ---- GEMM over this chunk: 32x32x16 MFMA ----
        int nks = ntap * 4;                      // k-steps of 16
        int m = lane & 31;
        for (int s = 0; s < nks; ++s) {
            const unsigned short* ap = w_bf + (ow + m) * CK_ + koff + s * 16 + ph * 8;
            bf16x8 a = *(const bf16x8*)ap;
            bf16x8 bb = *(const bf16x8*)&sS[(pw + m) * SSTRB + (s * 16 + ph * 8) * 2];
            acc = __builtin_amdgcn_mfma_f32_32x32x16_bf16(a, bb, acc, 0, 0, 0);
        }
        __syncthreads();
        tap0 = 5; koff = 320;
    }

    // Epilogue: C/D layout col=lane&31, row=(reg&3)+8*(reg>>2)+4*(lane>>5)
    int col = lane & 31;
    int rbase = 4 * ph;
    #pragma unroll
    for (int r = 0; r < 16; ++r) {
        int row = (r & 3) + 8 * (r >> 2) + rbase;
        out[((size_t)(b * CO_ + ow + row)) * HW_ + p0 + pw + col] = acc[r];
    }
}

extern "C" void kernel_launch(void* const* d_in, const int* in_sizes, int n_in,
                              void* d_out, int out_size, void* d_ws, size_t ws_size,
                              hipStream_t stream)
{
    const float* x     = (const float*)d_in[0];
    const float* w_off = (const float*)d_in[1];
    const float* b_off = (const float*)d_in[2];
    const float* w_dcn = (const float*)d_in[3];
    float* out = (float*)d_out;

    size_t offs = (size_t)B_ * KK_ * HW_;        // 1,179,648
    float* pdy = (float*)d_ws;
    float* pdx = pdy + offs;
    float* pm  = pdx + offs;
    unsigned* xt = (unsigned*)(pm + offs);                    // 8.39M bf16 = 4.19M dwords
    unsigned short* w_bf = (unsigned short*)(xt + (size_t)B_ * HW_ * 32);

    prep_w<<<144, 256, 0, stream>>>(w_dcn, w_bf);
    transpose_bf<<<B_ * 256, 256, 0, stream>>>(x, xt);
    off_conv3<<<B_ * 64 * 3, 256, 0, stream>>>(x, w_off, b_off, pdy, pdx, pm);
    dcn3<<<B_ * 256, 256, 0, stream>>>(xt, pdy, pdx, pm, w_bf, out);
}

// Round 4
// 198.464 us; speedup vs baseline: 13.7984x; 1.6704x over previous
//
#include <hip/hip_runtime.h>
#include <math.h>

#define B_  8
#define C_  64
#define H_  128
#define W_  128
#define KK_ 9
#define CO_ 64
#define HW_ (H_*W_)
#define CK_ 576

typedef __attribute__((ext_vector_type(8))) short bf16x8;
typedef __attribute__((ext_vector_type(4))) float f32x4;

__device__ inline float blo(unsigned u){ union{unsigned v;float f;}c; c.v = u<<16;          return c.f; }
__device__ inline float bhi(unsigned u){ union{unsigned v;float f;}c; c.v = u & 0xffff0000u; return c.f; }
__device__ inline unsigned pack_bf16x2(float a, float b){
    union{float f;unsigned u;} ua, ub; ua.f=a; ub.f=b;
    unsigned ra = ua.u + 0x7fffu + ((ua.u>>16)&1u);
    unsigned rb = ub.u + 0x7fffu + ((ub.u>>16)&1u);
    return (ra>>16) | (rb & 0xffff0000u);
}
__device__ inline unsigned short f2bf(float f){
    union{float f;unsigned u;} uu; uu.f = f;
    unsigned rr = uu.u + 0x7fffu + ((uu.u>>16)&1u);
    return (unsigned short)(rr >> 16);
}

// ---- prep_w: w_dcn (o,c,tap) fp32 -> w_bf[o][tap*64+c] bf16 ----
__global__ __launch_bounds__(256) void prep_w(const float* __restrict__ w_dcn,
                                              unsigned short* __restrict__ w_bf)
{
    int i = blockIdx.x * 256 + threadIdx.x;       // 64*576 = 36864
    int o = i / CK_;
    int r = i % CK_;
    int tap = r >> 6;
    int c = r & 63;
    w_bf[i] = f2bf(w_dcn[o * CK_ + c * 9 + tap]);
}

// ---- prep_woff: w_off (27,c,tap) fp32 -> wA[32][tap*64+c] bf16 (pad 0) ----
__global__ __launch_bounds__(256) void prep_woff(const float* __restrict__ w_off,
                                                 unsigned short* __restrict__ wA)
{
    int i = blockIdx.x * 256 + threadIdx.x;       // 32*576 = 18432
    int o = i / CK_;
    int k = i % CK_;
    int tap = k >> 6;
    int c = k & 63;
    float v = (o < 27) ? w_off[o * CK_ + c * 9 + tap] : 0.f;
    wA[i] = f2bf(v);
}

// ---- transpose_bf: x NCHW fp32 -> xt NHWC bf16 (as dwords, 2 ch each) ----
__global__ __launch_bounds__(256) void transpose_bf(const float* __restrict__ x,
                                                    unsigned* __restrict__ xt)
{
    __shared__ float tb[64 * 65];
    int b = blockIdx.x >> 8;
    int pixbase = (blockIdx.x & 255) * 64;
    #pragma unroll
    for (int i = 0; i < 16; ++i) {
        int idx = i * 256 + threadIdx.x;
        int c = idx >> 6, pix = idx & 63;
        tb[c * 65 + pix] = x[((size_t)(b * C_ + c)) * HW_ + pixbase + pix];
    }
    __syncthreads();
    #pragma unroll
    for (int i = 0; i < 8; ++i) {
        int idx = i * 256 + threadIdx.x;
        int pix = idx >> 5, cp = idx & 31;
        float f0 = tb[(2*cp)   * 65 + pix];
        float f1 = tb[(2*cp+1) * 65 + pix];
        xt[((size_t)b * HW_ + pixbase + pix) * 32 + cp] = pack_bf16x2(f0, f1);
    }
}

// ---- off_conv4: offset conv as MFMA GEMM. Block = 1 row (128 px) x 32 o ----
#define OCSTR 144     // tile col stride bytes (64ch*2B + 16 pad): 4-bank spread, 16B aligned
__global__ __launch_bounds__(256) void off_conv4(
    const unsigned* __restrict__ xt, const unsigned short* __restrict__ wA,
    const float* __restrict__ b_off, float* __restrict__ pdy,
    float* __restrict__ pdx, float* __restrict__ pm)
{
    __shared__ __align__(16) unsigned char tile[3 * 132 * OCSTR];  // 57 KB
    int b = blockIdx.x >> 7;
    int y = blockIdx.x & 127;
    int t = threadIdx.x;
    int lane = t & 63, w = t >> 6;
    int m = lane & 15, q = lane >> 4;
    int o0  = (w & 1) * 16;       // wave's o-tile
    int pxb = (w >> 1) * 64;      // wave's px half

    // Preload all A-frags (weights) for this wave's o-tile: 18 x 16 B = 72 VGPR
    bf16x8 A[18];
    #pragma unroll
    for (int s = 0; s < 18; ++s)
        A[s] = *(const bf16x8*)(wA + (o0 + m) * CK_ + s * 32 + q * 8);

    // Stage x rows y-1..y+1, cols -1..130, 64 ch bf16 (zero halo)
    for (int i = t; i < 3 * 132 * 8; i += 256) {
        int r   = i / (132 * 8);
        int rem = i - r * (132 * 8);
        int col = rem >> 3;
        int qq  = rem & 7;
        int yy = y - 1 + r;
        int xx = col - 1;
        uint4 v = make_uint4(0, 0, 0, 0);
        if (yy >= 0 && yy < H_ && xx >= 0 && xx < W_)
            v = *(const uint4*)(xt + ((size_t)(b * HW_ + yy * W_ + xx)) * 32 + qq * 4);
        *(uint4*)&tile[(r * 132 + col) * OCSTR + qq * 16] = v;
    }
    __syncthreads();

    f32x4 acc[4] = {};
    #pragma unroll
    for (int s = 0; s < 18; ++s) {
        const int tap = s >> 1, c0 = (s & 1) * 32;
        const int ky = tap / 3, kx = tap % 3;
        #pragma unroll
        for (int nt = 0; nt < 4; ++nt) {
            int px = pxb + nt * 16 + m;
            bf16x8 bb = *(const bf16x8*)&tile[(ky * 132 + px + kx) * OCSTR + (c0 + q * 8) * 2];
            acc[nt] = __builtin_amdgcn_mfma_f32_16x16x32_bf16(A[s], bb, acc[nt], 0, 0, 0);
        }
    }

    // Epilogue: C/D 16x16: col(px)=lane&15, row(o)=q*4+reg
    #pragma unroll
    for (int nt = 0; nt < 4; ++nt) {
        int px = pxb + nt * 16 + m;
        int p = y * W_ + px;
        #pragma unroll
        for (int r = 0; r < 4; ++r) {
            int j = o0 + q * 4 + r;
            if (j < 27) {
                float v = acc[nt][r] + b_off[j];
                if (j < 18) {
                    int k = j >> 1;
                    float* dst = (j & 1) ? pdx : pdy;   // om[2k]=dy, om[2k+1]=dx
                    dst[(b * KK_ + k) * HW_ + p] = v;
                } else {
                    pm[(b * KK_ + (j - 18)) * HW_ + p] = 1.f / (1.f + expf(-v));
                }
            }
        }
    }
}

// ---- dcn4: bilinear sample + MFMA 16x16x32, A (weights) preloaded in regs --
#define SSTR4 400     // sS row stride bytes (192k*2B + 16 pad), 16B aligned
__global__ __launch_bounds__(256) void dcn4(
    const unsigned* __restrict__ xt,
    const float* __restrict__ pdy, const float* __restrict__ pdx,
    const float* __restrict__ pm,
    const unsigned short* __restrict__ w_bf,
    float* __restrict__ out)
{
    __shared__ __align__(16) unsigned char sS[64 * SSTR4];  // 25.6 KB
    __shared__ float4 scr_w[576];
    __shared__ int    scr_o[576];

    int tile = blockIdx.x;
    int b  = tile >> 8;
    int p0 = (tile & 255) * 64;
    int y  = p0 >> 7;
    int x0 = p0 & 127;
    int t  = threadIdx.x;
    int lane = t & 63, w = t >> 6;
    int m = lane & 15, q = lane >> 4;
    int o0 = w * 16;              // wave's 16 out-channels
    int cp = lane & 31, ph = lane >> 5;

    // Phase 0: offsets -> bilinear corner weights + packed byte-offsets
    for (int i = t; i < 576; i += 256) {
        int k = i >> 6, sp = i & 63;
        int oidx = (b * KK_ + k) * HW_ + p0 + sp;
        float dy = pdy[oidx], dx = pdx[oidx], mk = pm[oidx];
        float py = dy + (float)(y - 1 + k / 3);
        float px = dx + (float)(x0 + sp - 1 + k % 3);
        float fy = floorf(py), fx = floorf(px);
        int iy = (int)fy, ix = (int)fx;
        float ay = py - fy, ax = px - fx;
        float wy0 = (iy >= 0  && iy < H_)     ? (1.f - ay) : 0.f;
        float wy1 = (iy >= -1 && iy < H_ - 1) ? ay         : 0.f;
        float wx0 = (ix >= 0  && ix < W_)     ? (1.f - ax) : 0.f;
        float wx1 = (ix >= -1 && ix < W_ - 1) ? ax         : 0.f;
        int iy0 = min(max(iy, 0), H_ - 1);
        int iy1 = min(max(iy + 1, 0), H_ - 1);
        int ix0 = min(max(ix, 0), W_ - 1);
        int ix1 = min(max(ix + 1, 0), W_ - 1);
        scr_w[i] = make_float4(wy0*wx0*mk, wy0*wx1*mk, wy1*wx0*mk, wy1*wx1*mk);
        int off00 = (iy0 * W_ + ix0) * 128;
        scr_o[i] = off00 | ((ix1 != ix0) << 22) | ((iy1 != iy0) << 23);
    }

    // Preload all A-frags for this wave's o-tile (coalesced 64B-per-row loads)
    bf16x8 A[18];
    #pragma unroll
    for (int s = 0; s < 18; ++s)
        A[s] = *(const bf16x8*)(w_bf + (o0 + m) * CK_ + s * 32 + q * 8);

    __syncthreads();

    const unsigned char* xb = (const unsigned char*)xt + (size_t)b * HW_ * 128;
    f32x4 acc[4] = {};

    #pragma unroll
    for (int chunk = 0; chunk < 3; ++chunk) {
        const int tap0 = chunk * 3;
        // ---- sampling: 3 taps x 64 px; 2 px per wave-iter ----
        for (int it = 0; it < 24; ++it) {
            int pi = w * 24 + it;
            int ktl = pi >> 5;
            int sp  = (pi & 31) * 2 + ph;
            int idx = (tap0 + ktl) * 64 + sp;
            float4 w4 = scr_w[idx];
            int pk = scr_o[idx];
            int off00 = pk & 0x3FFFFF;
            int dxb = (pk >> 15) & 128;
            int dyb = (pk >> 9)  & 16384;
            const unsigned char* a00 = xb + off00 + cp * 4;
            unsigned u00 = *(const unsigned*)(a00);
            unsigned u01 = *(const unsigned*)(a00 + dxb);
            unsigned u10 = *(const unsigned*)(a00 + dyb);
            unsigned u11 = *(const unsigned*)(a00 + dyb + dxb);
            float lo = w4.x*blo(u00) + w4.y*blo(u01) + w4.z*blo(u10) + w4.w*blo(u11);
            float hi = w4.x*bhi(u00) + w4.y*bhi(u01) + w4.z*bhi(u10) + w4.w*bhi(u11);
            *(unsigned*)&sS[sp * SSTR4 + ktl * 128 + cp * 4] = pack_bf16x2(lo, hi);
        }
        __syncthreads();

        // ---- GEMM: 6 k-steps x 4 px-tiles ----
        #pragma unroll
        for (int s = 0; s < 6; ++s) {
            #pragma unroll
            for (int nt = 0; nt < 4; ++nt) {
                bf16x8 bb = *(const bf16x8*)&sS[(nt * 16 + m) * SSTR4 + s * 64 + q * 16];
                acc[nt] = __builtin_amdgcn_mfma_f32_16x16x32_bf16(A[chunk * 6 + s], bb, acc[nt], 0, 0, 0);
            }
        }
        __syncthreads();
    }

    // Epilogue: col(px)=lane&15, row(o)=q*4+reg
    #pragma unroll
    for (int nt = 0; nt < 4; ++nt) {
        #pragma unroll
        for (int r = 0; r < 4; ++r) {
            int o = o0 + q * 4 + r;
            out[((size_t)(b * CO_ + o)) * HW_ + p0 + nt * 16 + m] = acc[nt][r];
        }
    }
}

extern "C" void kernel_launch(void* const* d_in, const int* in_sizes, int n_in,
                              void* d_out, int out_size, void* d_ws, size_t ws_size,
                              hipStream_t stream)
{
    const float* x     = (const float*)d_in[0];
    const float* w_off = (const float*)d_in[1];
    const float* b_off = (const float*)d_in[2];
    const float* w_dcn = (const float*)d_in[3];
    float* out = (float*)d_out;

    size_t offs = (size_t)B_ * KK_ * HW_;        // 1,179,648
    float* pdy = (float*)d_ws;
    float* pdx = pdy + offs;
    float* pm  = pdx + offs;
    unsigned* xt = (unsigned*)(pm + offs);                       // B*HW*32 dwords
    unsigned short* w_bf = (unsigned short*)(xt + (size_t)B_ * HW_ * 32);
    unsigned short* wA   = w_bf + 64 * CK_;

    prep_w<<<144, 256, 0, stream>>>(w_dcn, w_bf);
    prep_woff<<<72, 256, 0, stream>>>(w_off, wA);
    transpose_bf<<<B_ * 256, 256, 0, stream>>>(x, xt);
    off_conv4<<<B_ * H_, 256, 0, stream>>>(xt, wA, b_off, pdy, pdx, pm);
    dcn4<<<B_ * 256, 256, 0, stream>>>(xt, pdy, pdx, pm, w_bf, out);
}

// Round 5
// 198.248 us; speedup vs baseline: 13.8135x; 1.0011x over previous
//
#include <hip/hip_runtime.h>
#include <math.h>

#define B_  8
#define C_  64
#define H_  128
#define W_  128
#define KK_ 9
#define CO_ 64
#define HW_ (H_*W_)
#define CK_ 576

typedef __attribute__((ext_vector_type(8))) short bf16x8;
typedef __attribute__((ext_vector_type(4))) float f32x4;

__device__ inline float blo(unsigned u){ union{unsigned v;float f;}c; c.v = u<<16;          return c.f; }
__device__ inline float bhi(unsigned u){ union{unsigned v;float f;}c; c.v = u & 0xffff0000u; return c.f; }
__device__ inline unsigned pack_bf16x2(float a, float b){
    union{float f;unsigned u;} ua, ub; ua.f=a; ub.f=b;
    unsigned ra = ua.u + 0x7fffu + ((ua.u>>16)&1u);
    unsigned rb = ub.u + 0x7fffu + ((ub.u>>16)&1u);
    return (ra>>16) | (rb & 0xffff0000u);
}
__device__ inline unsigned short f2bf(float f){
    union{float f;unsigned u;} uu; uu.f = f;
    unsigned rr = uu.u + 0x7fffu + ((uu.u>>16)&1u);
    return (unsigned short)(rr >> 16);
}

// ---- prep_w: w_dcn (o,c,tap) fp32 -> w_bf[o][tap*64+c] bf16 ----
__global__ __launch_bounds__(256) void prep_w(const float* __restrict__ w_dcn,
                                              unsigned short* __restrict__ w_bf)
{
    int i = blockIdx.x * 256 + threadIdx.x;       // 64*576 = 36864
    int o = i / CK_;
    int r = i % CK_;
    int tap = r >> 6;
    int c = r & 63;
    w_bf[i] = f2bf(w_dcn[o * CK_ + c * 9 + tap]);
}

// ---- prep_woff: w_off (27,c,tap) fp32 -> wA[32][tap*64+c] bf16 (pad 0) ----
__global__ __launch_bounds__(256) void prep_woff(const float* __restrict__ w_off,
                                                 unsigned short* __restrict__ wA)
{
    int i = blockIdx.x * 256 + threadIdx.x;       // 32*576 = 18432
    int o = i / CK_;
    int k = i % CK_;
    int tap = k >> 6;
    int c = k & 63;
    float v = (o < 27) ? w_off[o * CK_ + c * 9 + tap] : 0.f;
    wA[i] = f2bf(v);
}

// ---- transpose_bf: x NCHW fp32 -> xt NHWC bf16 (as dwords, 2 ch each) ----
__global__ __launch_bounds__(256) void transpose_bf(const float* __restrict__ x,
                                                    unsigned* __restrict__ xt)
{
    __shared__ float tb[64 * 65];
    int b = blockIdx.x >> 8;
    int pixbase = (blockIdx.x & 255) * 64;
    #pragma unroll
    for (int i = 0; i < 16; ++i) {
        int idx = i * 256 + threadIdx.x;
        int c = idx >> 6, pix = idx & 63;
        tb[c * 65 + pix] = x[((size_t)(b * C_ + c)) * HW_ + pixbase + pix];
    }
    __syncthreads();
    #pragma unroll
    for (int i = 0; i < 8; ++i) {
        int idx = i * 256 + threadIdx.x;
        int pix = idx >> 5, cp = idx & 31;
        float f0 = tb[(2*cp)   * 65 + pix];
        float f1 = tb[(2*cp+1) * 65 + pix];
        xt[((size_t)b * HW_ + pixbase + pix) * 32 + cp] = pack_bf16x2(f0, f1);
    }
}

// ---- off_conv5: stageless offset conv. A-frags in regs, B-frags from global.
// Block = 1 row (128 px) x 32 o. No LDS, no barrier.
__global__ __launch_bounds__(256) void off_conv5(
    const unsigned* __restrict__ xt, const unsigned short* __restrict__ wA,
    const float* __restrict__ b_off, float* __restrict__ pdy,
    float* __restrict__ pdx, float* __restrict__ pm)
{
    int b = blockIdx.x >> 7;
    int y = blockIdx.x & 127;
    int t = threadIdx.x;
    int lane = t & 63, w = t >> 6;
    int m = lane & 15, q = lane >> 4;
    int o0  = (w & 1) * 16;       // wave's o-tile
    int pxb = (w >> 1) * 64;      // wave's px half

    // Preload all 18 A-frags (72 VGPR): coalesced 64B rows
    bf16x8 A[18];
    #pragma unroll
    for (int s = 0; s < 18; ++s)
        A[s] = *(const bf16x8*)(wA + (o0 + m) * CK_ + s * 32 + q * 8);

    f32x4 acc[4] = {};
    #pragma unroll
    for (int ky = 0; ky < 3; ++ky) {
        int yy = y + ky - 1;
        if (yy >= 0 && yy < H_) {
            const unsigned short* xr =
                (const unsigned short*)(xt + ((size_t)(b * HW_ + yy * W_)) * 32);
            #pragma unroll
            for (int kx = 0; kx < 3; ++kx) {
                #pragma unroll
                for (int nt = 0; nt < 4; ++nt) {
                    int base = pxb + nt * 16;
                    int xx = base + m + kx - 1;
                    int s2 = (ky * 3 + kx) * 2;
                    bf16x8 b0, b1;
                    if ((base == 0 && kx == 0) || (base == 112 && kx == 2)) {
                        // edge frag (wave-uniform branch): clamp + zero-select
                        int xc = min(max(xx, 0), W_ - 1);
                        const unsigned short* p = xr + xc * 64;
                        b0 = *(const bf16x8*)(p + q * 8);
                        b1 = *(const bf16x8*)(p + 32 + q * 8);
                        if (xx != xc) {
                            b0 = (bf16x8){0,0,0,0,0,0,0,0};
                            b1 = (bf16x8){0,0,0,0,0,0,0,0};
                        }
                    } else {
                        const unsigned short* p = xr + xx * 64;
                        b0 = *(const bf16x8*)(p + q * 8);
                        b1 = *(const bf16x8*)(p + 32 + q * 8);
                    }
                    acc[nt] = __builtin_amdgcn_mfma_f32_16x16x32_bf16(A[s2],     b0, acc[nt], 0, 0, 0);
                    acc[nt] = __builtin_amdgcn_mfma_f32_16x16x32_bf16(A[s2 + 1], b1, acc[nt], 0, 0, 0);
                }
            }
        }
    }

    // Epilogue: C/D 16x16: col(px)=m, row(o)=q*4+reg
    #pragma unroll
    for (int nt = 0; nt < 4; ++nt) {
        int px = pxb + nt * 16 + m;
        int p = y * W_ + px;
        #pragma unroll
        for (int r = 0; r < 4; ++r) {
            int j = o0 + q * 4 + r;
            if (j < 27) {
                float v = acc[nt][r] + b_off[j];
                if (j < 18) {
                    int k = j >> 1;
                    float* dst = (j & 1) ? pdx : pdy;   // om[2k]=dy, om[2k+1]=dx
                    dst[(b * KK_ + k) * HW_ + p] = v;
                } else {
                    pm[(b * KK_ + (j - 18)) * HW_ + p] = 1.f / (1.f + expf(-v));
                }
            }
        }
    }
}

// ---- dcn5: bilinear sample (4 ch/lane, dwordx2) + MFMA 16x16x32 ----
#define SSTR4 400     // sS row stride bytes (192k*2B + 16 pad), 16B aligned
__global__ __launch_bounds__(256) void dcn5(
    const unsigned* __restrict__ xt,
    const float* __restrict__ pdy, const float* __restrict__ pdx,
    const float* __restrict__ pm,
    const unsigned short* __restrict__ w_bf,
    float* __restrict__ out)
{
    __shared__ __align__(16) unsigned char sS[64 * SSTR4];  // 25.6 KB
    __shared__ float4 scr_w[576];
    __shared__ int    scr_o[576];

    int tile = blockIdx.x;
    int b  = tile >> 8;
    int p0 = (tile & 255) * 64;
    int y  = p0 >> 7;
    int x0 = p0 & 127;
    int t  = threadIdx.x;
    int lane = t & 63, w = t >> 6;
    int m = lane & 15, q = lane >> 4;
    int o0 = w * 16;              // wave's 16 out-channels
    int cq = lane & 15;           // channel quad (4 ch = 2 dwords)
    int g  = lane >> 4;           // pixel-tap sub-index (4 per wave-iter)

    // Phase 0: offsets -> bilinear corner weights + packed byte-offsets
    for (int i = t; i < 576; i += 256) {
        int k = i >> 6, sp = i & 63;
        int oidx = (b * KK_ + k) * HW_ + p0 + sp;
        float dy = pdy[oidx], dx = pdx[oidx], mk = pm[oidx];
        float py = dy + (float)(y - 1 + k / 3);
        float px = dx + (float)(x0 + sp - 1 + k % 3);
        float fy = floorf(py), fx = floorf(px);
        int iy = (int)fy, ix = (int)fx;
        float ay = py - fy, ax = px - fx;
        float wy0 = (iy >= 0  && iy < H_)     ? (1.f - ay) : 0.f;
        float wy1 = (iy >= -1 && iy < H_ - 1) ? ay         : 0.f;
        float wx0 = (ix >= 0  && ix < W_)     ? (1.f - ax) : 0.f;
        float wx1 = (ix >= -1 && ix < W_ - 1) ? ax         : 0.f;
        int iy0 = min(max(iy, 0), H_ - 1);
        int iy1 = min(max(iy + 1, 0), H_ - 1);
        int ix0 = min(max(ix, 0), W_ - 1);
        int ix1 = min(max(ix + 1, 0), W_ - 1);
        scr_w[i] = make_float4(wy0*wx0*mk, wy0*wx1*mk, wy1*wx0*mk, wy1*wx1*mk);
        int off00 = (iy0 * W_ + ix0) * 128;
        scr_o[i] = off00 | ((ix1 != ix0) << 22) | ((iy1 != iy0) << 23);
    }

    // Preload all A-frags for this wave's o-tile
    bf16x8 A[18];
    #pragma unroll
    for (int s = 0; s < 18; ++s)
        A[s] = *(const bf16x8*)(w_bf + (o0 + m) * CK_ + s * 32 + q * 8);

    __syncthreads();

    const unsigned char* xb = (const unsigned char*)xt + (size_t)b * HW_ * 128;
    f32x4 acc[4] = {};

    #pragma unroll
    for (int chunk = 0; chunk < 3; ++chunk) {
        const int tap0 = chunk * 3;
        // ---- sampling: 3 taps x 64 px; 4 pixel-taps x 16 ch-quads per iter --
        for (int it = 0; it < 12; ++it) {
            int pi = (w * 12 + it) * 4 + g;       // 0..191
            int ktl = pi >> 6;
            int sp  = pi & 63;
            int idx = (tap0 + ktl) * 64 + sp;
            float4 w4 = scr_w[idx];
            int pk = scr_o[idx];
            int off00 = pk & 0x3FFFFF;
            int dxb = (pk >> 15) & 128;
            int dyb = (pk >> 9)  & 16384;
            const unsigned char* a00 = xb + off00 + cq * 8;
            uint2 u00 = *(const uint2*)(a00);
            uint2 u01 = *(const uint2*)(a00 + dxb);
            uint2 u10 = *(const uint2*)(a00 + dyb);
            uint2 u11 = *(const uint2*)(a00 + dyb + dxb);
            float l0 = w4.x*blo(u00.x) + w4.y*blo(u01.x) + w4.z*blo(u10.x) + w4.w*blo(u11.x);
            float h0 = w4.x*bhi(u00.x) + w4.y*bhi(u01.x) + w4.z*bhi(u10.x) + w4.w*bhi(u11.x);
            float l1 = w4.x*blo(u00.y) + w4.y*blo(u01.y) + w4.z*blo(u10.y) + w4.w*blo(u11.y);
            float h1 = w4.x*bhi(u00.y) + w4.y*bhi(u01.y) + w4.z*bhi(u10.y) + w4.w*bhi(u11.y);
            uint2 o2;
            o2.x = pack_bf16x2(l0, h0);
            o2.y = pack_bf16x2(l1, h1);
            *(uint2*)&sS[sp * SSTR4 + ktl * 128 + cq * 8] = o2;
        }
        __syncthreads();

        // ---- GEMM: 6 k-steps x 4 px-tiles ----
        #pragma unroll
        for (int s = 0; s < 6; ++s) {
            #pragma unroll
            for (int nt = 0; nt < 4; ++nt) {
                bf16x8 bb = *(const bf16x8*)&sS[(nt * 16 + m) * SSTR4 + s * 64 + q * 16];
                acc[nt] = __builtin_amdgcn_mfma_f32_16x16x32_bf16(A[chunk * 6 + s], bb, acc[nt], 0, 0, 0);
            }
        }
        __syncthreads();
    }

    // Epilogue: col(px)=lane&15, row(o)=q*4+reg
    #pragma unroll
    for (int nt = 0; nt < 4; ++nt) {
        #pragma unroll
        for (int r = 0; r < 4; ++r) {
            int o = o0 + q * 4 + r;
            out[((size_t)(b * CO_ + o)) * HW_ + p0 + nt * 16 + m] = acc[nt][r];
        }
    }
}

extern "C" void kernel_launch(void* const* d_in, const int* in_sizes, int n_in,
                              void* d_out, int out_size, void* d_ws, size_t ws_size,
                              hipStream_t stream)
{
    const float* x     = (const float*)d_in[0];
    const float* w_off = (const float*)d_in[1];
    const float* b_off = (const float*)d_in[2];
    const float* w_dcn = (const float*)d_in[3];
    float* out = (float*)d_out;

    size_t offs = (size_t)B_ * KK_ * HW_;        // 1,179,648
    float* pdy = (float*)d_ws;
    float* pdx = pdy + offs;
    float* pm  = pdx + offs;
    unsigned* xt = (unsigned*)(pm + offs);                       // B*HW*32 dwords
    unsigned short* w_bf = (unsigned short*)(xt + (size_t)B_ * HW_ * 32);
    unsigned short* wA   = w_bf + 64 * CK_;

    prep_w<<<144, 256, 0, stream>>>(w_dcn, w_bf);
    prep_woff<<<72, 256, 0, stream>>>(w_off, wA);
    transpose_bf<<<B_ * 256, 256, 0, stream>>>(x, xt);
    off_conv5<<<B_ * H_, 256, 0, stream>>>(xt, wA, b_off, pdy, pdx, pm);
    dcn5<<<B_ * 256, 256, 0, stream>>>(xt, pdy, pdx, pm, w_bf, out);
}